// Round 2
// baseline (501.500 us; speedup 1.0000x reference)
//
#include <hip/hip_runtime.h>
#include <math.h>

#define BLOCK 256
#define PBOUND 0.99999f /* 1 - 1e-5 */

__device__ __forceinline__ float artanh_clamped(float n) {
    float z = fminf(n, PBOUND);
    return 0.5f * __logf((1.0f + z) / (1.0f - z));
}

// tanh for n >= 0 via expf (avoids libm tanhf call bloat)
__device__ __forceinline__ float tanh_pos(float n) {
    float e = __expf(-2.0f * n);
    return (1.0f - e) / (1.0f + e);
}

// pairwise-tree sum of squares (cuts the serial dependent-FMA chain)
template <int D>
__device__ __forceinline__ float sumsq_tree(const float* v) {
    float t[D];
#pragma unroll
    for (int i = 0; i < D; ++i) t[i] = v[i] * v[i];
#pragma unroll
    for (int s = D / 2; s > 0; s >>= 1) {
#pragma unroll
        for (int i = 0; i < s; ++i) t[i] += t[i + s];
    }
    return t[0];
}

// logmap0 in place: v <- artanh(min(|v|,B)) * v / |v|
template <int D>
__device__ __forceinline__ void logmap_inplace(float* v) {
    float n = fmaxf(sqrtf(sumsq_tree<D>(v)), 1e-15f);
    float s = artanh_clamped(n) / n;
#pragma unroll
    for (int k = 0; k < D; ++k) v[k] *= s;
}

template <int D>
__device__ __forceinline__ void expmap_inplace(float* y) {
    float n = fmaxf(sqrtf(sumsq_tree<D>(y)), 1e-15f);
    float s = tanh_pos(n) / n;
#pragma unroll
    for (int k = 0; k < D; ++k) y[k] *= s;
}

// y[J] = u[K] @ W[K][J]; u in registers (all indices static), W wave-uniform -> s_load
template <int K, int J>
__device__ __forceinline__ void matvec_reg(const float* __restrict__ W,
                                           const float* u, float* y) {
#pragma unroll
    for (int j = 0; j < J; ++j) y[j] = 0.0f;
#pragma unroll
    for (int k = 0; k < K; ++k) {
        const float uk = u[k];
        const float* wr = W + k * J;
#pragma unroll
        for (int j = 0; j < J; ++j) y[j] = fmaf(uk, wr[j], y[j]);
    }
}

// x <- mobius_add(x, y); tree-reduced dot products
template <int D>
__device__ __forceinline__ void mobius_add_inplace(float* x, const float* y) {
    float tx[D], ty[D], txy[D];
#pragma unroll
    for (int k = 0; k < D; ++k) {
        tx[k] = x[k] * x[k];
        ty[k] = y[k] * y[k];
        txy[k] = x[k] * y[k];
    }
#pragma unroll
    for (int s = D / 2; s > 0; s >>= 1) {
#pragma unroll
        for (int i = 0; i < s; ++i) {
            tx[i] += tx[i + s];
            ty[i] += ty[i + s];
            txy[i] += txy[i + s];
        }
    }
    float x2 = tx[0], y2 = ty[0], xy = txy[0];
    float a = 1.0f + 2.0f * xy + y2;
    float b = 1.0f - x2;
    float den = fmaxf(fmaf(x2, y2, 1.0f + 2.0f * xy), 1e-15f);
    float inv = 1.0f / den;
#pragma unroll
    for (int k = 0; k < D; ++k) x[k] = (a * x[k] + b * y[k]) * inv;
}

// x <- mobius_add(x, bias) with bias a wave-uniform global row (s_load path)
template <int D>
__device__ __forceinline__ void mobius_add_bias(float* x, const float* __restrict__ bias) {
    float tx[D], ty[D], txy[D];
#pragma unroll
    for (int k = 0; k < D; ++k) {
        float bk = bias[k];
        tx[k] = x[k] * x[k];
        ty[k] = bk * bk;
        txy[k] = x[k] * bk;
    }
#pragma unroll
    for (int s = D / 2; s > 0; s >>= 1) {
#pragma unroll
        for (int i = 0; i < s; ++i) {
            tx[i] += tx[i + s];
            ty[i] += ty[i + s];
            txy[i] += txy[i + s];
        }
    }
    float x2 = tx[0], y2 = ty[0], xy = txy[0];
    float a = 1.0f + 2.0f * xy + y2;
    float b = 1.0f - x2;
    float den = fmaxf(fmaf(x2, y2, 1.0f + 2.0f * xy), 1e-15f);
    float inv = 1.0f / den;
#pragma unroll
    for (int k = 0; k < D; ++k) x[k] = (a * x[k] + b * bias[k]) * inv;
}

// __launch_bounds__(256, 2): 2 waves/EU -> 8 waves/CU, caps VGPR at ~256 (no spill
// headroom issues; measured live set ~160-200).
__global__ void __launch_bounds__(BLOCK, 2) poincare_mlp_kernel(
    const float* __restrict__ x1, const float* __restrict__ x2,
    const float* __restrict__ Wc1, const float* __restrict__ Wc2,
    const float* __restrict__ bc, const float* __restrict__ W0,
    const float* __restrict__ b0, const float* __restrict__ W1,
    const float* __restrict__ b1, float* __restrict__ out, int nrows) {
    const int row = blockIdx.x * BLOCK + threadIdx.x;
    if (row >= nrows) return;

    float h1[64], h2[64];

    // ---- branch 1: h1 = expmap0(logmap0(x1) @ Wc1)
    {
        float v[32];
        const float4* p = (const float4*)(x1 + (size_t)row * 32);
#pragma unroll
        for (int i = 0; i < 8; ++i) {
            float4 t = p[i];
            v[4 * i + 0] = t.x; v[4 * i + 1] = t.y;
            v[4 * i + 2] = t.z; v[4 * i + 3] = t.w;
        }
        logmap_inplace<32>(v);
        matvec_reg<32, 64>(Wc1, v, h1);
    }
    expmap_inplace<64>(h1);

    // ---- branch 2: h2 = expmap0(logmap0(x2) @ Wc2)
    {
        float v[32];
        const float4* p = (const float4*)(x2 + (size_t)row * 32);
#pragma unroll
        for (int i = 0; i < 8; ++i) {
            float4 t = p[i];
            v[4 * i + 0] = t.x; v[4 * i + 1] = t.y;
            v[4 * i + 2] = t.z; v[4 * i + 3] = t.w;
        }
        logmap_inplace<32>(v);
        matvec_reg<32, 64>(Wc2, v, h2);
    }
    expmap_inplace<64>(h2);

    // ---- concat: h = mobius_add(mobius_add(h1, h2), bc)
    mobius_add_inplace<64>(h1, h2);
    mobius_add_bias<64>(h1, bc);

    // ---- layer 0: h = poincare_linear(h, W0, b0)
    logmap_inplace<64>(h1);
    matvec_reg<64, 64>(W0, h1, h2);
    expmap_inplace<64>(h2);
    mobius_add_bias<64>(h2, b0);

    // ---- layer 1: out = poincare_linear(h, W1, b1)
    logmap_inplace<64>(h2);
    float y[32];
    matvec_reg<64, 32>(W1, h2, y);
    expmap_inplace<32>(y);
    mobius_add_bias<32>(y, b1);

    float4* q = (float4*)(out + (size_t)row * 32);
#pragma unroll
    for (int i = 0; i < 8; ++i) {
        float4 t;
        t.x = y[4 * i + 0]; t.y = y[4 * i + 1];
        t.z = y[4 * i + 2]; t.w = y[4 * i + 3];
        q[i] = t;
    }
}

extern "C" void kernel_launch(void* const* d_in, const int* in_sizes, int n_in,
                              void* d_out, int out_size, void* d_ws, size_t ws_size,
                              hipStream_t stream) {
    const float* x1  = (const float*)d_in[0];
    const float* x2  = (const float*)d_in[1];
    const float* Wc1 = (const float*)d_in[2];
    const float* Wc2 = (const float*)d_in[3];
    const float* bc  = (const float*)d_in[4];
    const float* W0  = (const float*)d_in[5];
    const float* b0  = (const float*)d_in[6];
    const float* W1  = (const float*)d_in[7];
    const float* b1  = (const float*)d_in[8];
    float* out = (float*)d_out;

    const int nrows = in_sizes[0] / 32;
    const int nblocks = (nrows + BLOCK - 1) / BLOCK;
    poincare_mlp_kernel<<<nblocks, BLOCK, 0, stream>>>(
        x1, x2, Wc1, Wc2, bc, W0, b0, W1, b1, out, nrows);
}

// Round 3
// 328.090 us; speedup vs baseline: 1.5285x; 1.5285x over previous
//
#include <hip/hip_runtime.h>
#include <math.h>

// ---------------------------------------------------------------------------
// MFMA formulation: one wave processes 16 rows. Matvecs via
// mfma_f32_16x16x32_bf16 with 3-term bf16-split products (hi/lo) for ~fp32
// accuracy. Weights are pre-arranged into B-fragment layout in d_ws by a
// setup kernel. Cross-lane reductions via shfl_xor over 16-lane groups.
// Norms propagated analytically through mobius/expmap to halve reductions.
// ---------------------------------------------------------------------------

typedef short bf16x8 __attribute__((ext_vector_type(8)));
typedef float f32x4  __attribute__((ext_vector_type(4)));

#define MFMA16(A, B, C) __builtin_amdgcn_mfma_f32_16x16x32_bf16((A), (B), (C), 0, 0, 0)
#define PBOUND 0.99999f /* 1 - 1e-5 */

static __device__ __forceinline__ unsigned short f2bf(float x) {
    unsigned u = __builtin_bit_cast(unsigned, x);
    u += 0x7FFFu + ((u >> 16) & 1u); // RNE
    return (unsigned short)(u >> 16);
}
static __device__ __forceinline__ float bf2f(unsigned short h) {
    unsigned u = (unsigned)h << 16;
    return __builtin_bit_cast(float, u);
}
static __device__ __forceinline__ float artanh_c(float n) {
    float z = fminf(n, PBOUND);
    return 0.5f * __logf((1.0f + z) / (1.0f - z));
}
static __device__ __forceinline__ float tanh_pos(float n) {
    float e = __expf(-2.0f * n);
    return (1.0f - e) / (1.0f + e);
}
// sum over the 16-lane group (lanes sharing lane>>4)
static __device__ __forceinline__ float red16(float v) {
    v += __shfl_xor(v, 1);
    v += __shfl_xor(v, 2);
    v += __shfl_xor(v, 4);
    v += __shfl_xor(v, 8);
    return v;
}

// split fp32 -> bf16 hi + bf16 lo fragments
static __device__ __forceinline__ void split8(const float* u, bf16x8& ah, bf16x8& al) {
#pragma unroll
    for (int j = 0; j < 8; ++j) {
        unsigned short hi = f2bf(u[j]);
        ah[j] = (short)hi;
        al[j] = (short)f2bf(u[j] - bf2f(hi));
    }
}

// ---- per-stage helpers on D-layout data (lane holds col=16t+(lane&15),
// ---- rows (lane>>4)*4+r). NT = number of 16-col tiles.

// expmap in place; outputs x2[r] = |result|^2 (scalar per row)
template <int NT>
static __device__ __forceinline__ void expmap_d(f32x4* acc, float* x2) {
#pragma unroll
    for (int r = 0; r < 4; ++r) {
        float p = 0.0f;
#pragma unroll
        for (int t = 0; t < NT; ++t) p = fmaf(acc[t][r], acc[t][r], p);
        p = red16(p);
        float n = fmaxf(sqrtf(p), 1e-15f);
        float th = tanh_pos(n);
        float s = th / n;
        x2[r] = th * th;
#pragma unroll
        for (int t = 0; t < NT; ++t) acc[t][r] *= s;
    }
}

// x <- mobius_add(x, y); x2,y2 known scalars; updates x2 analytically
template <int NT>
static __device__ __forceinline__ void mobius_d(f32x4* x, const f32x4* y,
                                                float* x2, const float* y2) {
#pragma unroll
    for (int r = 0; r < 4; ++r) {
        float pxy = 0.0f;
#pragma unroll
        for (int t = 0; t < NT; ++t) pxy = fmaf(x[t][r], y[t][r], pxy);
        pxy = red16(pxy);
        float X = x2[r], Y = y2[r];
        float a = 1.0f + 2.0f * pxy + Y;
        float b = 1.0f - X;
        float den = fmaxf(fmaf(X, Y, 1.0f + 2.0f * pxy), 1e-15f);
        float inv = 1.0f / den;
#pragma unroll
        for (int t = 0; t < NT; ++t) x[t][r] = (a * x[t][r] + b * y[t][r]) * inv;
        x2[r] = (a * a * X + 2.0f * a * b * pxy + b * b * Y) * (inv * inv);
    }
}

// x <- mobius_add(x, bias); bias per-lane bv[NT] (col-indexed), |bias|^2 = y2
template <int NT>
static __device__ __forceinline__ void mobius_bias(f32x4* x, const float* bv,
                                                   float* x2, float y2) {
#pragma unroll
    for (int r = 0; r < 4; ++r) {
        float pxy = 0.0f;
#pragma unroll
        for (int t = 0; t < NT; ++t) pxy = fmaf(x[t][r], bv[t], pxy);
        pxy = red16(pxy);
        float X = x2[r];
        float a = 1.0f + 2.0f * pxy + y2;
        float b = 1.0f - X;
        float den = fmaxf(fmaf(X, y2, 1.0f + 2.0f * pxy), 1e-15f);
        float inv = 1.0f / den;
#pragma unroll
        for (int t = 0; t < NT; ++t) x[t][r] = fmaf(b, bv[t], a * x[t][r]) * inv;
        x2[r] = (a * a * X + 2.0f * a * b * pxy + b * b * y2) * (inv * inv);
    }
}

// logmap in place with known |x|^2
template <int NT>
static __device__ __forceinline__ void logmap_d(f32x4* x, const float* x2) {
#pragma unroll
    for (int r = 0; r < 4; ++r) {
        float n = fmaxf(sqrtf(x2[r]), 1e-15f);
        float s = artanh_c(n) / n;
#pragma unroll
        for (int t = 0; t < NT; ++t) x[t][r] *= s;
    }
}

// ---------------------------------------------------------------------------
// Setup kernel: arrange all weight matrices into B-fragment layout, bf16
// hi/lo split. Logical frag f: lane L holds W[kt*32 + (L>>4)*8 + j][nt*16 + (L&15)].
//  f 0-3 : Wc1 (K=32,N=64) nt=f        f 4-7 : Wc2 nt=f-4
//  f 8-15: W0  (K=64,N=64) kt=(f-8)>>2 nt=(f-8)&3
//  f16-19: W1  (K=64,N=32) kt=(f-16)>>1 nt=(f-16)&1
// Physical frag p = 2f (hi), 2f+1 (lo); 512 shorts each.
// ---------------------------------------------------------------------------
__global__ void build_frags(const float* __restrict__ Wc1, const float* __restrict__ Wc2,
                            const float* __restrict__ W0, const float* __restrict__ W1,
                            unsigned short* __restrict__ out) {
    int tid = blockIdx.x * blockDim.x + threadIdx.x;
    if (tid >= 40 * 512) return;
    int p = tid >> 9;
    int within = tid & 511;
    int lane = within >> 3, j = within & 7;
    int f = p >> 1, part = p & 1;
    const float* W;
    int N, kt, nt;
    if (f < 4)       { W = Wc1; N = 64; kt = 0;            nt = f; }
    else if (f < 8)  { W = Wc2; N = 64; kt = 0;            nt = f - 4; }
    else if (f < 16) { W = W0;  N = 64; kt = (f - 8) >> 2; nt = (f - 8) & 3; }
    else             { W = W1;  N = 32; kt = (f - 16) >> 1; nt = (f - 16) & 1; }
    int k = kt * 32 + (lane >> 4) * 8 + j;
    int n = nt * 16 + (lane & 15);
    float w = W[k * N + n];
    unsigned short hi = f2bf(w);
    out[tid] = part ? f2bf(w - bf2f(hi)) : hi;
}

// ---------------------------------------------------------------------------
// Main kernel: 256 threads = 4 waves, each wave owns one 16-row tile per
// iteration; grid-stride over tiles. W0 frags persistent in VGPRs; branch/W1
// frags reloaded per tile (L1-hot) to cap register pressure.
// ---------------------------------------------------------------------------
__global__ void __launch_bounds__(256, 2) poincare_mfma(
    const float* __restrict__ x1, const float* __restrict__ x2,
    const float* __restrict__ bc, const float* __restrict__ b0,
    const float* __restrict__ b1, const unsigned short* frags,
    float* out, int ntiles) {
    // per-wave transpose buffer: 16 rows x 64 cols fp32, stride 68
    // (writes: 2-way bank aliasing = free; reads: 16B-aligned b128)
    __shared__ float tb[4][16 * 68];
    const int lane = threadIdx.x & 63;
    const int wid = threadIdx.x >> 6;
    const int m = lane & 15, q = lane >> 4;
    float* tbuf = tb[wid];

    const bf16x8* F = (const bf16x8*)frags; // F[p*64 + lane]

    // persistent: W0 fragments (64 VGPRs)
    bf16x8 w0h[2][4], w0l[2][4];
#pragma unroll
    for (int kt = 0; kt < 2; ++kt)
#pragma unroll
        for (int t = 0; t < 4; ++t) {
            int f = 8 + kt * 4 + t;
            w0h[kt][t] = F[(2 * f) * 64 + lane];
            w0l[kt][t] = F[(2 * f + 1) * 64 + lane];
        }

    // biases in col-layout + their squared norms (once)
    float bcv[4], b0v[4], b1v[2];
#pragma unroll
    for (int t = 0; t < 4; ++t) { bcv[t] = bc[t * 16 + m]; b0v[t] = b0[t * 16 + m]; }
#pragma unroll
    for (int t = 0; t < 2; ++t) b1v[t] = b1[t * 16 + m];
    float bc2, b02, b12;
    {
        float p = 0.0f;
#pragma unroll
        for (int t = 0; t < 4; ++t) p = fmaf(bcv[t], bcv[t], p);
        bc2 = red16(p);
        p = 0.0f;
#pragma unroll
        for (int t = 0; t < 4; ++t) p = fmaf(b0v[t], b0v[t], p);
        b02 = red16(p);
        p = fmaf(b1v[0], b1v[0], b1v[1] * b1v[1]);
        b12 = red16(p);
    }

    for (int bt = blockIdx.x; bt * 4 < ntiles; bt += gridDim.x) {
        const int tile = bt * 4 + wid;
        const bool active = tile < ntiles;
        const int row0 = (active ? tile : 0) * 16;

        // ---- branch inputs: load 8 floats (A-frag element positions), logmap
        bf16x8 a1h, a1l, a2h, a2l;
        {
            const float4* p4 = (const float4*)(x1 + (size_t)(row0 + m) * 32 + q * 8);
            float4 va = p4[0], vb = p4[1];
            float v[8] = {va.x, va.y, va.z, va.w, vb.x, vb.y, vb.z, vb.w};
            float ss = 0.0f;
#pragma unroll
            for (int j = 0; j < 8; ++j) ss = fmaf(v[j], v[j], ss);
            ss += __shfl_xor(ss, 16);
            ss += __shfl_xor(ss, 32);
            float n = fmaxf(sqrtf(ss), 1e-15f);
            float s = artanh_c(n) / n;
#pragma unroll
            for (int j = 0; j < 8; ++j) v[j] *= s;
            split8(v, a1h, a1l);
        }
        {
            const float4* p4 = (const float4*)(x2 + (size_t)(row0 + m) * 32 + q * 8);
            float4 va = p4[0], vb = p4[1];
            float v[8] = {va.x, va.y, va.z, va.w, vb.x, vb.y, vb.z, vb.w};
            float ss = 0.0f;
#pragma unroll
            for (int j = 0; j < 8; ++j) ss = fmaf(v[j], v[j], ss);
            ss += __shfl_xor(ss, 16);
            ss += __shfl_xor(ss, 32);
            float n = fmaxf(sqrtf(ss), 1e-15f);
            float s = artanh_c(n) / n;
#pragma unroll
            for (int j = 0; j < 8; ++j) v[j] *= s;
            split8(v, a2h, a2l);
        }

        // ---- branch matvecs (reload Wc frags each tile: L1-hot, saves VGPRs)
        f32x4 h1[4], h2[4];
#pragma unroll
        for (int t = 0; t < 4; ++t) {
            bf16x8 bh = F[(2 * t) * 64 + lane];
            bf16x8 bl = F[(2 * t + 1) * 64 + lane];
            f32x4 c = {0.0f, 0.0f, 0.0f, 0.0f};
            c = MFMA16(a1h, bh, c);
            c = MFMA16(a1l, bh, c);
            c = MFMA16(a1h, bl, c);
            h1[t] = c;
        }
#pragma unroll
        for (int t = 0; t < 4; ++t) {
            bf16x8 bh = F[(2 * (4 + t)) * 64 + lane];
            bf16x8 bl = F[(2 * (4 + t) + 1) * 64 + lane];
            f32x4 c = {0.0f, 0.0f, 0.0f, 0.0f};
            c = MFMA16(a2h, bh, c);
            c = MFMA16(a2l, bh, c);
            c = MFMA16(a2h, bl, c);
            h2[t] = c;
        }

        float X2[4], Y2[4];
        expmap_d<4>(h1, X2);
        expmap_d<4>(h2, Y2);
        mobius_d<4>(h1, h2, X2, Y2);
        mobius_bias<4>(h1, bcv, X2, bc2);
        logmap_d<4>(h1, X2); // h1 now = u0 (input to W0)

        // ---- transpose #1: D-layout -> A-frags via LDS
#pragma unroll
        for (int r = 0; r < 4; ++r)
#pragma unroll
            for (int t = 0; t < 4; ++t)
                tbuf[(q * 4 + r) * 68 + t * 16 + m] = h1[t][r];
        __syncthreads();
        bf16x8 m0h[2], m0l[2];
#pragma unroll
        for (int kt = 0; kt < 2; ++kt) {
            const float4* rp = (const float4*)&tbuf[m * 68 + kt * 32 + q * 8];
            float4 c0 = rp[0], c1 = rp[1];
            float u[8] = {c0.x, c0.y, c0.z, c0.w, c1.x, c1.y, c1.z, c1.w};
            split8(u, m0h[kt], m0l[kt]);
        }

        // ---- layer 0 matvec (persistent W0 frags)
        f32x4 hm[4];
#pragma unroll
        for (int t = 0; t < 4; ++t) {
            f32x4 c = {0.0f, 0.0f, 0.0f, 0.0f};
#pragma unroll
            for (int kt = 0; kt < 2; ++kt) {
                c = MFMA16(m0h[kt], w0h[kt][t], c);
                c = MFMA16(m0l[kt], w0h[kt][t], c);
                c = MFMA16(m0h[kt], w0l[kt][t], c);
            }
            hm[t] = c;
        }
        float M2[4];
        expmap_d<4>(hm, M2);
        mobius_bias<4>(hm, b0v, M2, b02);
        logmap_d<4>(hm, M2); // hm now = u1 (input to W1)

        // ---- transpose #2
        __syncthreads(); // protect tbuf until all reads of transpose #1 done
#pragma unroll
        for (int r = 0; r < 4; ++r)
#pragma unroll
            for (int t = 0; t < 4; ++t)
                tbuf[(q * 4 + r) * 68 + t * 16 + m] = hm[t][r];
        __syncthreads();
        bf16x8 m1h[2], m1l[2];
#pragma unroll
        for (int kt = 0; kt < 2; ++kt) {
            const float4* rp = (const float4*)&tbuf[m * 68 + kt * 32 + q * 8];
            float4 c0 = rp[0], c1 = rp[1];
            float u[8] = {c0.x, c0.y, c0.z, c0.w, c1.x, c1.y, c1.z, c1.w};
            split8(u, m1h[kt], m1l[kt]);
        }
        __syncthreads(); // tbuf free for next iteration

        // ---- layer 1 matvec (reload W1 frags)
        f32x4 ho[2];
#pragma unroll
        for (int t = 0; t < 2; ++t) {
            f32x4 c = {0.0f, 0.0f, 0.0f, 0.0f};
#pragma unroll
            for (int kt = 0; kt < 2; ++kt) {
                int f = 16 + kt * 2 + t;
                bf16x8 bh = F[(2 * f) * 64 + lane];
                bf16x8 bl = F[(2 * f + 1) * 64 + lane];
                c = MFMA16(m1h[kt], bh, c);
                c = MFMA16(m1l[kt], bh, c);
                c = MFMA16(m1h[kt], bl, c);
            }
            ho[t] = c;
        }
        float O2[4];
        expmap_d<2>(ho, O2);
        mobius_bias<2>(ho, b1v, O2, b12);

        // ---- store (col=16t+m of row q*4+r: 4x64B segments per instr)
        if (active) {
#pragma unroll
            for (int r = 0; r < 4; ++r)
#pragma unroll
                for (int t = 0; t < 2; ++t)
                    out[(size_t)(row0 + q * 4 + r) * 32 + t * 16 + m] = ho[t][r];
        }
    }
}

extern "C" void kernel_launch(void* const* d_in, const int* in_sizes, int n_in,
                              void* d_out, int out_size, void* d_ws, size_t ws_size,
                              hipStream_t stream) {
    const float* x1  = (const float*)d_in[0];
    const float* x2  = (const float*)d_in[1];
    const float* Wc1 = (const float*)d_in[2];
    const float* Wc2 = (const float*)d_in[3];
    const float* bc  = (const float*)d_in[4];
    const float* W0  = (const float*)d_in[5];
    const float* b0  = (const float*)d_in[6];
    const float* W1  = (const float*)d_in[7];
    const float* b1  = (const float*)d_in[8];
    float* out = (float*)d_out;
    unsigned short* frags = (unsigned short*)d_ws; // 40 KB

    const int nrows  = in_sizes[0] / 32;
    const int ntiles = nrows / 16; // N=524288 -> 32768 (assumes %16==0)

    build_frags<<<80, 256, 0, stream>>>(Wc1, Wc2, W0, W1, frags);
    poincare_mfma<<<2048, 256, 0, stream>>>(x1, x2, bc, b0, b1, frags, out, ntiles);
}

// Round 4
// 232.695 us; speedup vs baseline: 2.1552x; 1.4100x over previous
//
#include <hip/hip_runtime.h>
#include <math.h>

// ---------------------------------------------------------------------------
// Round 4: weights in A-operand (W^T), activations in B-operand.
//  - D layout: col = lane&15 = data row  -> per-row reductions = 16 in-lane
//    FMA + 2 shfl; per-row scalar math 1x per stage (was 4x).
//  - Layer-to-layer: D regs feed next MFMA's B-frag DIRECTLY; the required
//    feature permutation is folded into the next layer's weight K-order
//    (kperm, applied at fragment-build time). Zero LDS, zero barriers.
//  - All logmap scales / mobius 1/den folded into a running per-row scalar
//    lambda; vectors stay raw (2 FMA/el per mobius).
// ---------------------------------------------------------------------------

typedef short bf16x8 __attribute__((ext_vector_type(8)));
typedef float f32x4  __attribute__((ext_vector_type(4)));

#define MFMA16(A, B, C) __builtin_amdgcn_mfma_f32_16x16x32_bf16((A), (B), (C), 0, 0, 0)
#define PBOUND 0.99999f /* 1 - 1e-5 */

static __device__ __forceinline__ float artanh_c(float n) {
    float z = fminf(n, PBOUND);
    return 0.5f * __logf((1.0f + z) / (1.0f - z));
}
static __device__ __forceinline__ float tanh_pos(float n) {
    float e = __expf(-2.0f * n);
    return (1.0f - e) / (1.0f + e);
}
// sum across the 4 quads (lanes ^16, ^32); result broadcast to all 4
static __device__ __forceinline__ float red4q(float v) {
    v += __shfl_xor(v, 16);
    v += __shfl_xor(v, 32);
    return v;
}
// truncation split: hi = top 16 bits, lo = bf16(x - hi). ~4 ops.
static __device__ __forceinline__ void split_trunc(float x, short* h, short* l) {
    unsigned u = __builtin_bit_cast(unsigned, x);
    *h = (short)(u >> 16);
    float fh = __builtin_bit_cast(float, u & 0xFFFF0000u);
    float r = x - fh;
    unsigned ur = __builtin_bit_cast(unsigned, r);
    *l = (short)(ur >> 16);
}

// B-slot kk = 32*kt + 8q + jj holds natural feature kperm(kk) of the previous
// layer's D output (t = 2*kt + (jj>>2), r = jj&3, feature = 16t + 4q + r).
static __device__ __forceinline__ int kperm(int kk) {
    return 32 * (kk >> 5) + 16 * ((kk & 7) >> 2) + 4 * ((kk >> 3) & 3) + (kk & 3);
}

template <int NT>
static __device__ __forceinline__ float dotred(const f32x4* a, const f32x4* b) {
    float p = 0.0f;
#pragma unroll
    for (int t = 0; t < NT; ++t)
#pragma unroll
        for (int r = 0; r < 4; ++r) p = fmaf(a[t][r], b[t][r], p);
    return red4q(p);
}

// expmap with pending scale: true vec = lam*d. Updates lam, X2 (true |.|^2).
template <int NT>
static __device__ __forceinline__ void expmap_fold(const f32x4* d, float& lam, float& X2) {
    float p = 0.0f;
#pragma unroll
    for (int t = 0; t < NT; ++t)
#pragma unroll
        for (int r = 0; r < 4; ++r) p = fmaf(d[t][r], d[t][r], p);
    p = red4q(p);
    float nU = fmaxf(lam * sqrtf(p), 1e-15f);
    float th = tanh_pos(nU);
    lam = lam * th / nU;
    X2 = th * th;
}

static __device__ __forceinline__ void logmap_fold(float& lam, float X2) {
    float n = fmaxf(sqrtf(X2), 1e-15f);
    lam *= artanh_c(n) / n;
}

// d <- raw(mobius_add(lam*d, bias)); lam <- 1/den; X2 updated analytically
template <int NT>
static __device__ __forceinline__ void mobius_bias_fold(f32x4* d, const f32x4* bv,
                                                        float& lam, float& X2, float b2) {
    float C = dotred<NT>(d, bv);
    float xy = lam * C;
    float a = 1.0f + 2.0f * xy + b2;
    float b = 1.0f - X2;
    float den = fmaxf(fmaf(X2, b2, 1.0f + 2.0f * xy), 1e-15f);
    float inv = 1.0f / den;
    float A = a * lam;
#pragma unroll
    for (int t = 0; t < NT; ++t)
#pragma unroll
        for (int r = 0; r < 4; ++r) d[t][r] = fmaf(A, d[t][r], b * bv[t][r]);
    lam = inv;
    X2 = (a * a * X2 + 2.0f * a * b * xy + b * b * b2) * (inv * inv);
}

// split 16 D-regs into the two next-layer B-frag hi/lo pairs
static __device__ __forceinline__ void split_d16(const f32x4* d, bf16x8* bh, bf16x8* bl) {
#pragma unroll
    for (int kt = 0; kt < 2; ++kt)
#pragma unroll
        for (int jj = 0; jj < 8; ++jj) {
            short hh, ll;
            split_trunc(d[2 * kt + (jj >> 2)][jj & 3], &hh, &ll);
            bh[kt][jj] = hh;
            bl[kt][jj] = ll;
        }
}

// matvec with K=64 (2 kt blocks), NT output tiles; frags at logical id
// fbase + 2t + kt (hi = phys 2f, lo = 2f+1)
template <int NT>
static __device__ __forceinline__ void layer_mm(const bf16x8* __restrict__ F, int fbase,
                                                int lane, const bf16x8* ah,
                                                const bf16x8* al, f32x4* d) {
#pragma unroll
    for (int t = 0; t < NT; ++t) {
        f32x4 c = {0.0f, 0.0f, 0.0f, 0.0f};
#pragma unroll
        for (int kt = 0; kt < 2; ++kt) {
            int f = fbase + 2 * t + kt;
            bf16x8 wh = F[(2 * f) * 64 + lane];
            bf16x8 wl = F[(2 * f + 1) * 64 + lane];
            c = MFMA16(wh, ah[kt], c);
            c = MFMA16(wl, ah[kt], c);
            c = MFMA16(wh, al[kt], c);
        }
        d[t] = c;
    }
}

// branch: load x-row chunk (B-frag natural k), logmap fold, split, matvec
// (A = Wc^T frags at fbase..fbase+3), expmap fold.
static __device__ __forceinline__ void branch_stage(const float* __restrict__ x, size_t row,
                                                    int q, int lane, int fbase,
                                                    const bf16x8* __restrict__ F, f32x4* d,
                                                    float& lam, float& X2) {
    const float4* p4 = (const float4*)(x + row * 32 + q * 8);
    float4 va = p4[0], vb = p4[1];
    float v[8] = {va.x, va.y, va.z, va.w, vb.x, vb.y, vb.z, vb.w};
    float n2 = 0.0f;
#pragma unroll
    for (int i = 0; i < 8; ++i) n2 = fmaf(v[i], v[i], n2);
    n2 = red4q(n2);
    float n = fmaxf(sqrtf(n2), 1e-15f);
    lam = artanh_c(n) / n; // logmap scale, folded past the matvec
    bf16x8 bh, bl;
#pragma unroll
    for (int i = 0; i < 8; ++i) {
        short hh, ll;
        split_trunc(v[i], &hh, &ll);
        bh[i] = hh;
        bl[i] = ll;
    }
#pragma unroll
    for (int t = 0; t < 4; ++t) {
        bf16x8 wh = F[(2 * (fbase + t)) * 64 + lane];
        bf16x8 wl = F[(2 * (fbase + t) + 1) * 64 + lane];
        f32x4 c = {0.0f, 0.0f, 0.0f, 0.0f};
        c = MFMA16(wh, bh, c);
        c = MFMA16(wl, bh, c);
        c = MFMA16(wh, bl, c);
        d[t] = c;
    }
    expmap_fold<4>(d, lam, X2);
}

// ---------------------------------------------------------------------------
// Setup: weight fragments (A-operand layout, RNE hi/lo split; W0/W1 with
// kperm'd K) + bias squared norms.
//  logical f: 0-3 Wc1(t), 4-7 Wc2(t), 8-15 W0(t=(f-8)>>1, kt=(f-8)&1),
//             16-19 W1(t=(f-16)>>1, kt=(f-16)&1). phys 2f=hi, 2f+1=lo.
// ---------------------------------------------------------------------------
__global__ void build_frags(const float* __restrict__ Wc1, const float* __restrict__ Wc2,
                            const float* __restrict__ W0, const float* __restrict__ W1,
                            const float* __restrict__ bc, const float* __restrict__ b0,
                            const float* __restrict__ b1, unsigned short* __restrict__ fout,
                            float* __restrict__ norms) {
    int tid = blockIdx.x * blockDim.x + threadIdx.x;
    const int total = 40 * 512;
    if (tid < total) {
        int p = tid >> 9, within = tid & 511;
        int lane = within >> 3, jj = within & 7;
        int f = p >> 1, isLo = p & 1;
        int m = lane & 15, kq = lane >> 4;
        int kl = kq * 8 + jj; // A-frag k within the 32-block
        float w;
        if (f < 4)      w = Wc1[kl * 64 + f * 16 + m];
        else if (f < 8) w = Wc2[kl * 64 + (f - 4) * 16 + m];
        else if (f < 16) {
            int t = (f - 8) >> 1, kt = (f - 8) & 1;
            w = W0[kperm(32 * kt + kl) * 64 + t * 16 + m];
        } else {
            int t = (f - 16) >> 1, kt = (f - 16) & 1;
            w = W1[kperm(32 * kt + kl) * 32 + t * 16 + m];
        }
        unsigned u = __builtin_bit_cast(unsigned, w);
        unsigned r = u + (0x7FFFu + ((u >> 16) & 1u)); // RNE
        unsigned short hi = (unsigned short)(r >> 16);
        float fhi = __builtin_bit_cast(float, (unsigned)hi << 16);
        float res = w - fhi;
        unsigned ul = __builtin_bit_cast(unsigned, res);
        unsigned rl = ul + (0x7FFFu + ((ul >> 16) & 1u));
        fout[tid] = isLo ? (unsigned short)(rl >> 16) : hi;
    } else if (tid < total + 3) {
        int which = tid - total;
        const float* b = which == 0 ? bc : (which == 1 ? b0 : b1);
        int n = which == 2 ? 32 : 64;
        float s = 0.0f;
        for (int i = 0; i < n; ++i) s += b[i] * b[i];
        norms[which] = s;
    }
}

// ---------------------------------------------------------------------------
// Main: 4 waves/block, one 16-row tile per wave, no LDS, no barriers.
// ---------------------------------------------------------------------------
__global__ void __launch_bounds__(256, 4) poincare_mfma2(
    const float* __restrict__ x1, const float* __restrict__ x2,
    const float* __restrict__ bc, const float* __restrict__ b0,
    const float* __restrict__ b1, const unsigned short* __restrict__ frags,
    const float* __restrict__ norms, float* __restrict__ out, int ntiles) {
    const int lane = threadIdx.x & 63;
    const int wid = threadIdx.x >> 6;
    const int tile = blockIdx.x * 4 + wid;
    if (tile >= ntiles) return;
    const int j = lane & 15, q = lane >> 4;
    const size_t row = (size_t)tile * 16 + j;

    const bf16x8* F = (const bf16x8*)frags; // F[phys*64 + lane]
    const float bc2 = norms[0], b02 = norms[1], b12 = norms[2];

    // ---- branches
    f32x4 d1[4], d2[4];
    float lam1, X2, lam2, Y2;
    branch_stage(x1, row, q, lane, 0, F, d1, lam1, X2);
    branch_stage(x2, row, q, lane, 4, F, d2, lam2, Y2);

    // ---- mobius_add(h1, h2), scales folded
    {
        float C = dotred<4>(d1, d2);
        float xy = lam1 * lam2 * C;
        float a = 1.0f + 2.0f * xy + Y2;
        float b = 1.0f - X2;
        float den = fmaxf(fmaf(X2, Y2, 1.0f + 2.0f * xy), 1e-15f);
        float inv = 1.0f / den;
        float A = a * lam1, B = b * lam2;
#pragma unroll
        for (int t = 0; t < 4; ++t)
#pragma unroll
            for (int r = 0; r < 4; ++r) d1[t][r] = fmaf(A, d1[t][r], B * d2[t][r]);
        lam1 = inv;
        X2 = (a * a * X2 + 2.0f * a * b * xy + b * b * Y2) * (inv * inv);
    }
    // ---- + bc  (bias vectors load in natural feature order: f = 16t+4q+r)
    f32x4 bcv[4];
#pragma unroll
    for (int t = 0; t < 4; ++t) bcv[t] = *(const f32x4*)(bc + t * 16 + q * 4);
    mobius_bias_fold<4>(d1, bcv, lam1, X2, bc2);
    logmap_fold(lam1, X2);

    // ---- layer 0 (K=64, kperm'd weights; D feeds B-frags directly)
    bf16x8 ah[2], al[2];
    split_d16(d1, ah, al);
    f32x4 d0[4];
    layer_mm<4>(F, 8, lane, ah, al, d0);
    expmap_fold<4>(d0, lam1, X2);
    f32x4 b0v[4];
#pragma unroll
    for (int t = 0; t < 4; ++t) b0v[t] = *(const f32x4*)(b0 + t * 16 + q * 4);
    mobius_bias_fold<4>(d0, b0v, lam1, X2, b02);
    logmap_fold(lam1, X2);

    // ---- layer 1 (N=32)
    split_d16(d0, ah, al);
    f32x4 dO[2];
    layer_mm<2>(F, 16, lane, ah, al, dO);
    expmap_fold<2>(dO, lam1, X2);

    // ---- final mobius bias, inv folded into the store scale
    f32x4 b1v[2];
#pragma unroll
    for (int t = 0; t < 2; ++t) b1v[t] = *(const f32x4*)(b1 + t * 16 + q * 4);
    {
        float C = dotred<2>(dO, b1v);
        float xy = lam1 * C;
        float a = 1.0f + 2.0f * xy + b12;
        float b = 1.0f - X2;
        float den = fmaxf(fmaf(X2, b12, 1.0f + 2.0f * xy), 1e-15f);
        float inv = 1.0f / den;
        float F1 = inv * a * lam1, F2 = inv * b;
#pragma unroll
        for (int t = 0; t < 2; ++t) {
            f32x4 res;
#pragma unroll
            for (int r = 0; r < 4; ++r) res[r] = fmaf(F1, dO[t][r], F2 * b1v[t][r]);
            *(f32x4*)(out + row * 32 + t * 16 + q * 4) = res;
        }
    }
}

extern "C" void kernel_launch(void* const* d_in, const int* in_sizes, int n_in,
                              void* d_out, int out_size, void* d_ws, size_t ws_size,
                              hipStream_t stream) {
    const float* x1  = (const float*)d_in[0];
    const float* x2  = (const float*)d_in[1];
    const float* Wc1 = (const float*)d_in[2];
    const float* Wc2 = (const float*)d_in[3];
    const float* bc  = (const float*)d_in[4];
    const float* W0  = (const float*)d_in[5];
    const float* b0  = (const float*)d_in[6];
    const float* W1  = (const float*)d_in[7];
    const float* b1  = (const float*)d_in[8];
    float* out = (float*)d_out;

    unsigned short* frags = (unsigned short*)d_ws;            // 40 KB
    float* norms = (float*)((char*)d_ws + 40 * 512 * 2);      // 3 floats

    const int nrows  = in_sizes[0] / 32;
    const int ntiles = nrows / 16;
    const int nblocks = (ntiles + 3) / 4;

    build_frags<<<81, 256, 0, stream>>>(Wc1, Wc2, W0, W1, bc, b0, b1, frags, norms);
    poincare_mfma2<<<nblocks, 256, 0, stream>>>(x1, x2, bc, b0, b1, frags, norms, out, ntiles);
}